// Round 1
// baseline (213.299 us; speedup 1.0000x reference)
//
#include <hip/hip_runtime.h>

typedef __attribute__((ext_vector_type(8))) short bf16x8;
typedef __attribute__((ext_vector_type(4))) float f32x4;

static __device__ __forceinline__ unsigned short f2bf(float f) {
    union { float f; unsigned int u; } v; v.f = f;
    unsigned int r = v.u + 0x7FFFu + ((v.u >> 16) & 1u);
    return (unsigned short)(r >> 16);
}

#define NRW (27 * 16384)

// Repack Wq/Wk/Wv -> RW[conv][kh][kw][cc][g][o][8s] bf16 (B-frag-ready), Wo -> bf16 [o][c]
__global__ __launch_bounds__(256) void repack_k(const float* __restrict__ Wq, const float* __restrict__ Wk,
                                                const float* __restrict__ Wv, const float* __restrict__ Wo,
                                                unsigned short* __restrict__ RW, unsigned short* __restrict__ WoB) {
    int t = blockIdx.x * 256 + threadIdx.x;
    if (t < NRW) {
        int s = t & 7, o = (t >> 3) & 127, g = (t >> 10) & 3, cc = (t >> 12) & 3, tap = t >> 14;
        int conv = tap / 9, kk = tap % 9, kh = kk / 3, kw = kk % 3;
        int c = cc * 32 + g * 8 + s;
        const float* W = (conv == 0) ? Wq : ((conv == 1) ? Wk : Wv);
        RW[t] = f2bf(W[((o * 128 + c) * 3 + kh) * 3 + kw]);
    } else {
        int u = t - NRW;
        if (u < 16384) WoB[u] = f2bf(Wo[u]);
    }
}

// Fused QKV 3x3 conv, implicit GEMM. Block = (b, h): M=64 (w), N=384 (3 convs x 128 o), K=1152.
__global__ __launch_bounds__(256) void qkv_conv_k(const float* __restrict__ x, const unsigned short* __restrict__ RW,
                                                  const float* __restrict__ bq, const float* __restrict__ bk,
                                                  const float* __restrict__ bv,
                                                  unsigned short* __restrict__ q_ws, unsigned short* __restrict__ k_ws,
                                                  unsigned short* __restrict__ v_ws) {
    __shared__ unsigned short xs[3 * 66 * 128];  // [kh][w+1 (66 padded)][c], swizzled ^((row&7)<<4)
    const int tid = threadIdx.x;
    const int b = blockIdx.x >> 6, h = blockIdx.x & 63;
    for (int i = tid; i < 3 * 66 * 128; i += 256) xs[i] = 0;
    __syncthreads();
    for (int ch = tid; ch < 3 * 128 * 16; ch += 256) {
        int r3 = ch >> 11, rem = ch & 2047, c = rem >> 4, w4 = rem & 15;
        int hh = h - 1 + r3;
        if (hh >= 0 && hh < 64) {
            float4 v = *(const float4*)(x + ((b * 128 + c) * 64 + hh) * 64 + w4 * 4);
            float vv[4] = {v.x, v.y, v.z, v.w};
#pragma unroll
            for (int j = 0; j < 4; ++j) {
                int wr = w4 * 4 + j + 1;
                unsigned int byte = (unsigned int)(((r3 * 66 + wr) * 128 + c) * 2) ^ ((wr & 7) << 4);
                *(unsigned short*)((char*)xs + byte) = f2bf(vv[j]);
            }
        }
    }
    __syncthreads();
    const int lane = tid & 63, wave = tid >> 6;
    const int l15 = lane & 15, g = lane >> 4;
    f32x4 acc[4][6];
#pragma unroll
    for (int i = 0; i < 4; ++i)
#pragma unroll
        for (int j = 0; j < 6; ++j) acc[i][j] = (f32x4){0.f, 0.f, 0.f, 0.f};
#pragma unroll 1
    for (int kk = 0; kk < 9; ++kk) {
        const int kw = kk % 3;
#pragma unroll 1
        for (int cc = 0; cc < 4; ++cc) {
            bf16x8 a[4];
#pragma unroll
            for (int mf = 0; mf < 4; ++mf) {
                int wr = mf * 16 + l15 + kw;
                unsigned int byte = (unsigned int)((((kk / 3) * 66 + wr) * 128 + cc * 32 + g * 8) * 2) ^ ((wr & 7) << 4);
                a[mf] = *(const bf16x8*)((const char*)xs + byte);
            }
#pragma unroll
            for (int n6 = 0; n6 < 6; ++n6) {
                int nt = wave * 6 + n6;
                int conv = nt >> 3;
                int o = (nt * 16 + l15) & 127;
                bf16x8 bfr = *(const bf16x8*)(RW + ((((conv * 9 + kk) * 4 + cc) * 4 + g) * 128 + o) * 8);
#pragma unroll
                for (int mf = 0; mf < 4; ++mf)
                    acc[mf][n6] = __builtin_amdgcn_mfma_f32_16x16x32_bf16(a[mf], bfr, acc[mf][n6], 0, 0, 0);
            }
        }
    }
    const float SCALE = 0.08838834764831845f;  // 1/sqrt(128), folded into q
#pragma unroll
    for (int n6 = 0; n6 < 6; ++n6) {
        int nt = wave * 6 + n6;
        int conv = nt >> 3;
        int o = (nt * 16 + l15) & 127;
        float bias = (conv == 0) ? bq[o] : ((conv == 1) ? bk[o] : bv[o]);
#pragma unroll
        for (int mf = 0; mf < 4; ++mf) {
#pragma unroll
            for (int r = 0; r < 4; ++r) {
                int pos = h * 64 + mf * 16 + g * 4 + r;
                float val = acc[mf][n6][r] + bias;
                if (conv == 0)      q_ws[(b * 4096 + pos) * 128 + o] = f2bf(val * SCALE);
                else if (conv == 1) k_ws[(b * 4096 + pos) * 128 + o] = f2bf(val);
                else                v_ws[(b * 128 + o) * 4096 + pos] = f2bf(val);
            }
        }
    }
}

// Flash attention + fused 1x1 conv + bias + residual. Block = (b, 64-row q tile), 4 waves x 16 i-cols.
__global__ __launch_bounds__(256) void attn_k(const unsigned short* __restrict__ q_ws, const unsigned short* __restrict__ k_ws,
                                              const unsigned short* __restrict__ v_ws, const unsigned short* __restrict__ WoB,
                                              const float* __restrict__ bo, const float* __restrict__ x,
                                              float* __restrict__ out) {
    __shared__ unsigned short sK[64 * 128];  // [j][c] swz ^((j&7)<<4); reused as sOut [i][c] at end
    __shared__ unsigned short sV[128 * 64];  // [c][j] swz ^((c&7)<<4)
    __shared__ unsigned short sP[64 * 64];   // [i][j] swz ^((i&7)<<4)
    const int tid = threadIdx.x;
    const int b = blockIdx.x >> 6, qt = blockIdx.x & 63;
    const int ibase = qt * 64;
    const int lane = tid & 63, wave = tid >> 6;
    const int l15 = lane & 15, g = lane >> 4, g8 = (lane >> 4) * 8;
    const int wi = wave * 16;

    bf16x8 qf[4];
#pragma unroll
    for (int cc = 0; cc < 4; ++cc)
        qf[cc] = *(const bf16x8*)(q_ws + (b * 4096 + ibase + wi + l15) * 128 + cc * 32 + g8);

    f32x4 oac[8];
#pragma unroll
    for (int cf = 0; cf < 8; ++cf) oac[cf] = (f32x4){0.f, 0.f, 0.f, 0.f};
    float m = -1e30f, ssum = 0.f;

#pragma unroll 1
    for (int kt = 0; kt < 64; ++kt) {
        const int jb = kt * 64;
        __syncthreads();  // previous PV done before restaging
#pragma unroll
        for (int ii = 0; ii < 4; ++ii) {  // stage K tile [64][128]
            int idx = tid * 4 + ii;
            int j = idx >> 4, c16 = idx & 15;
            unsigned int byte = (unsigned int)(j * 256 + c16 * 16) ^ ((j & 7) << 4);
            *(uint4*)((char*)sK + byte) = *(const uint4*)(k_ws + (b * 4096 + jb + j) * 128 + c16 * 8);
        }
#pragma unroll
        for (int ii = 0; ii < 4; ++ii) {  // stage V tile [128][64] (channel-major source)
            int idx = tid * 4 + ii;
            int c = idx >> 3, j8 = idx & 7;
            unsigned int byte = (unsigned int)(c * 128 + j8 * 16) ^ ((c & 7) << 4);
            *(uint4*)((char*)sV + byte) = *(const uint4*)(v_ws + (b * 128 + c) * 4096 + jb + j8 * 8);
        }
        __syncthreads();
        // S^T[j][i] = K · Q^T  (swapped so softmax over j is mostly in-lane)
        f32x4 st[4];
#pragma unroll
        for (int jf = 0; jf < 4; ++jf) st[jf] = (f32x4){0.f, 0.f, 0.f, 0.f};
#pragma unroll
        for (int jf = 0; jf < 4; ++jf) {
#pragma unroll
            for (int cc = 0; cc < 4; ++cc) {
                int row = jf * 16 + l15;
                unsigned int byte = (unsigned int)((row * 128 + cc * 32 + g8) * 2) ^ ((row & 7) << 4);
                bf16x8 a = *(const bf16x8*)((const char*)sK + byte);
                st[jf] = __builtin_amdgcn_mfma_f32_16x16x32_bf16(a, qf[cc], st[jf], 0, 0, 0);
            }
        }
        // online softmax over j (16 in-lane values + 2 shuffles across 16-lane groups)
        float tmax = -1e30f;
#pragma unroll
        for (int jf = 0; jf < 4; ++jf)
#pragma unroll
            for (int r = 0; r < 4; ++r) tmax = fmaxf(tmax, st[jf][r]);
        tmax = fmaxf(tmax, __shfl_xor(tmax, 16));
        tmax = fmaxf(tmax, __shfl_xor(tmax, 32));
        float mnew = fmaxf(m, tmax);
        float corr = __expf(m - mnew);
        float psum = 0.f;
        unsigned short pb[4][4];
#pragma unroll
        for (int jf = 0; jf < 4; ++jf)
#pragma unroll
            for (int r = 0; r < 4; ++r) {
                float p = __expf(st[jf][r] - mnew);
                psum += p;
                pb[jf][r] = f2bf(p);
            }
        psum += __shfl_xor(psum, 16);
        psum += __shfl_xor(psum, 32);
        ssum = ssum * corr + psum;
        m = mnew;
#pragma unroll
        for (int cf = 0; cf < 8; ++cf) oac[cf] *= corr;
#pragma unroll
        for (int jf = 0; jf < 4; ++jf)
#pragma unroll
            for (int r = 0; r < 4; ++r) {
                int j = jf * 16 + g * 4 + r;
                unsigned int byte = (unsigned int)(((wi + l15) * 64 + j) * 2) ^ ((l15 & 7) << 4);
                *(unsigned short*)((char*)sP + byte) = pb[jf][r];
            }
        __syncthreads();
        // out2[c][i] += V' (A, [c][j]) x P^T (B, [j][i])
#pragma unroll
        for (int jc = 0; jc < 2; ++jc) {
            unsigned int bbyte = (unsigned int)(((wi + l15) * 64 + jc * 32 + g8) * 2) ^ ((l15 & 7) << 4);
            bf16x8 pfr = *(const bf16x8*)((const char*)sP + bbyte);
#pragma unroll
            for (int cf = 0; cf < 8; ++cf) {
                int row = cf * 16 + l15;
                unsigned int abyte = (unsigned int)((row * 64 + jc * 32 + g8) * 2) ^ ((row & 7) << 4);
                bf16x8 va = *(const bf16x8*)((const char*)sV + abyte);
                oac[cf] = __builtin_amdgcn_mfma_f32_16x16x32_bf16(va, pfr, oac[cf], 0, 0, 0);
            }
        }
    }
    // normalize, round-trip out2 through LDS as [i][c], then 1x1 conv + bias + residual
    float inv = 1.0f / ssum;
    unsigned short* sOut = sK;
#pragma unroll
    for (int cf = 0; cf < 8; ++cf)
#pragma unroll
        for (int r = 0; r < 4; ++r) {
            int c = cf * 16 + g * 4 + r;
            unsigned int byte = (unsigned int)(((wi + l15) * 128 + c) * 2) ^ ((l15 & 7) << 4);
            *(unsigned short*)((char*)sOut + byte) = f2bf(oac[cf][r] * inv);
        }
    __syncthreads();
    f32x4 a3[8];
#pragma unroll
    for (int of = 0; of < 8; ++of) a3[of] = (f32x4){0.f, 0.f, 0.f, 0.f};
#pragma unroll
    for (int cc = 0; cc < 4; ++cc) {
        unsigned int bbyte = (unsigned int)(((wi + l15) * 128 + cc * 32 + g8) * 2) ^ ((l15 & 7) << 4);
        bf16x8 bfr = *(const bf16x8*)((const char*)sOut + bbyte);
#pragma unroll
        for (int of = 0; of < 8; ++of) {
            bf16x8 wa = *(const bf16x8*)(WoB + (of * 16 + l15) * 128 + cc * 32 + g8);
            a3[of] = __builtin_amdgcn_mfma_f32_16x16x32_bf16(wa, bfr, a3[of], 0, 0, 0);
        }
    }
#pragma unroll
    for (int of = 0; of < 8; ++of) {
#pragma unroll
        for (int r = 0; r < 4; ++r) {
            int o = of * 16 + g * 4 + r;
            int gidx = (b * 128 + o) * 4096 + ibase + wi + l15;
            out[gidx] = a3[of][r] + bo[o] + x[gidx];
        }
    }
}

extern "C" void kernel_launch(void* const* d_in, const int* in_sizes, int n_in,
                              void* d_out, int out_size, void* d_ws, size_t ws_size,
                              hipStream_t stream) {
    const float* x  = (const float*)d_in[0];
    const float* Wq = (const float*)d_in[1];
    const float* bq = (const float*)d_in[2];
    const float* Wk = (const float*)d_in[3];
    const float* bk = (const float*)d_in[4];
    const float* Wv = (const float*)d_in[5];
    const float* bv = (const float*)d_in[6];
    const float* Wo = (const float*)d_in[7];
    const float* bo = (const float*)d_in[8];
    char* ws = (char*)d_ws;
    unsigned short* q_ws = (unsigned short*)(ws);              //  8 MB  [b][n][c] bf16 (pre-scaled)
    unsigned short* k_ws = (unsigned short*)(ws + 8388608);    //  8 MB  [b][n][c] bf16
    unsigned short* v_ws = (unsigned short*)(ws + 16777216);   //  8 MB  [b][c][n] bf16
    unsigned short* RW   = (unsigned short*)(ws + 25165824);   //  884 KB repacked qkv weights
    unsigned short* WoB  = (unsigned short*)(ws + 26050560);   //  32 KB  Wo bf16
    float* out = (float*)d_out;

    hipLaunchKernelGGL(repack_k, dim3(1792), dim3(256), 0, stream, Wq, Wk, Wv, Wo, RW, WoB);
    hipLaunchKernelGGL(qkv_conv_k, dim3(512), dim3(256), 0, stream, x, RW, bq, bk, bv, q_ws, k_ws, v_ws);
    hipLaunchKernelGGL(attn_k, dim3(512), dim3(256), 0, stream, q_ws, k_ws, v_ws, WoB, bo, x, out);
}

// Round 3
// 151.388 us; speedup vs baseline: 1.4090x; 1.4090x over previous
//
#include <hip/hip_runtime.h>

typedef __attribute__((ext_vector_type(8))) short bf16x8;
typedef __attribute__((ext_vector_type(4))) float f32x4;
typedef __attribute__((ext_vector_type(16))) float f32x16;

static __device__ __forceinline__ unsigned short f2bf(float f) {
    union { float f; unsigned int u; } v; v.f = f;
    unsigned int r = v.u + 0x7FFFu + ((v.u >> 16) & 1u);
    return (unsigned short)(r >> 16);
}

static __device__ __forceinline__ unsigned cvtpk_bf16(float lo, float hi) {
    unsigned r;
    asm("v_cvt_pk_bf16_f32 %0, %1, %2" : "=v"(r) : "v"(lo), "v"(hi));
    return r;
}

#define NRW (27 * 16384)

// Repack Wq/Wk/Wv -> RW[conv][kh][kw][cc][g][o][8s] bf16 (B-frag-ready), Wo -> bf16 [o][c]
__global__ __launch_bounds__(256) void repack_k(const float* __restrict__ Wq, const float* __restrict__ Wk,
                                                const float* __restrict__ Wv, const float* __restrict__ Wo,
                                                unsigned short* __restrict__ RW, unsigned short* __restrict__ WoB) {
    int t = blockIdx.x * 256 + threadIdx.x;
    if (t < NRW) {
        int s = t & 7, o = (t >> 3) & 127, g = (t >> 10) & 3, cc = (t >> 12) & 3, tap = t >> 14;
        int conv = tap / 9, kk = tap % 9, kh = kk / 3, kw = kk % 3;
        int c = cc * 32 + g * 8 + s;
        const float* W = (conv == 0) ? Wq : ((conv == 1) ? Wk : Wv);
        RW[t] = f2bf(W[((o * 128 + c) * 3 + kh) * 3 + kw]);
    } else {
        int u = t - NRW;
        if (u < 16384) WoB[u] = f2bf(Wo[u]);
    }
}

// Fused QKV 3x3 conv, implicit GEMM. Block = (b, h): M=64 (w), N=384 (3 convs x 128 o), K=1152.
__global__ __launch_bounds__(256) void qkv_conv_k(const float* __restrict__ x, const unsigned short* __restrict__ RW,
                                                  const float* __restrict__ bq, const float* __restrict__ bk,
                                                  const float* __restrict__ bv,
                                                  unsigned short* __restrict__ q_ws, unsigned short* __restrict__ k_ws,
                                                  unsigned short* __restrict__ v_ws) {
    __shared__ unsigned short xs[3 * 66 * 128];  // [kh][w+1 (66 padded)][c], swizzled ^((row&7)<<4)
    const int tid = threadIdx.x;
    const int b = blockIdx.x >> 6, h = blockIdx.x & 63;
    for (int i = tid; i < 3 * 66 * 128; i += 256) xs[i] = 0;
    __syncthreads();
    for (int ch = tid; ch < 3 * 128 * 16; ch += 256) {
        int r3 = ch >> 11, rem = ch & 2047, c = rem >> 4, w4 = rem & 15;
        int hh = h - 1 + r3;
        if (hh >= 0 && hh < 64) {
            float4 v = *(const float4*)(x + ((b * 128 + c) * 64 + hh) * 64 + w4 * 4);
            float vv[4] = {v.x, v.y, v.z, v.w};
#pragma unroll
            for (int j = 0; j < 4; ++j) {
                int wr = w4 * 4 + j + 1;
                unsigned int byte = (unsigned int)(((r3 * 66 + wr) * 128 + c) * 2) ^ ((wr & 7) << 4);
                *(unsigned short*)((char*)xs + byte) = f2bf(vv[j]);
            }
        }
    }
    __syncthreads();
    const int lane = tid & 63, wave = tid >> 6;
    const int l15 = lane & 15, g = lane >> 4;
    f32x4 acc[4][6];
#pragma unroll
    for (int i = 0; i < 4; ++i)
#pragma unroll
        for (int j = 0; j < 6; ++j) acc[i][j] = (f32x4){0.f, 0.f, 0.f, 0.f};
#pragma unroll 1
    for (int kk = 0; kk < 9; ++kk) {
        const int kw = kk % 3;
#pragma unroll 1
        for (int cc = 0; cc < 4; ++cc) {
            bf16x8 a[4];
#pragma unroll
            for (int mf = 0; mf < 4; ++mf) {
                int wr = mf * 16 + l15 + kw;
                unsigned int byte = (unsigned int)((((kk / 3) * 66 + wr) * 128 + cc * 32 + g * 8) * 2) ^ ((wr & 7) << 4);
                a[mf] = *(const bf16x8*)((const char*)xs + byte);
            }
#pragma unroll
            for (int n6 = 0; n6 < 6; ++n6) {
                int nt = wave * 6 + n6;
                int conv = nt >> 3;
                int o = (nt * 16 + l15) & 127;
                bf16x8 bfr = *(const bf16x8*)(RW + ((((conv * 9 + kk) * 4 + cc) * 4 + g) * 128 + o) * 8);
#pragma unroll
                for (int mf = 0; mf < 4; ++mf)
                    acc[mf][n6] = __builtin_amdgcn_mfma_f32_16x16x32_bf16(a[mf], bfr, acc[mf][n6], 0, 0, 0);
            }
        }
    }
    const float SCALE = 0.08838834764831845f;  // 1/sqrt(128), folded into q
#pragma unroll
    for (int n6 = 0; n6 < 6; ++n6) {
        int nt = wave * 6 + n6;
        int conv = nt >> 3;
        int o = (nt * 16 + l15) & 127;
        float bias = (conv == 0) ? bq[o] : ((conv == 1) ? bk[o] : bv[o]);
#pragma unroll
        for (int mf = 0; mf < 4; ++mf) {
#pragma unroll
            for (int r = 0; r < 4; ++r) {
                int pos = h * 64 + mf * 16 + g * 4 + r;
                float val = acc[mf][n6][r] + bias;
                if (conv == 0)      q_ws[(b * 4096 + pos) * 128 + o] = f2bf(val * SCALE);
                else if (conv == 1) k_ws[(b * 4096 + pos) * 128 + o] = f2bf(val);
                else                v_ws[(b * 128 + o) * 4096 + pos] = f2bf(val);
            }
        }
    }
}

#define AS1C(p) ((const __attribute__((address_space(1))) void*)(p))
#define AS3(p)  ((__attribute__((address_space(3))) void*)(p))

// Flash attention (split-KV across 2 wave-halves) + fused 1x1 conv + bias + residual.
// Block = (b, 128-row q tile), 8 waves = 4 wi (32 i) x 2 wj (64 j). KV tile = 128 j,
// double-buffered in LDS with prefetch issued at iteration top (one barrier per iter).
// P exchange is fully in-register (cvt_pk + shfl_xor 32): no sP, no write->read race.
// LDS: K0@0 V0@32K K1@64K V1@96K (32KB each), sRed@128K. Epilogue reuses buffers.
__global__ __launch_bounds__(512, 2) void attn_k(
    const unsigned short* __restrict__ q_ws, const unsigned short* __restrict__ k_ws,
    const unsigned short* __restrict__ v_ws, const unsigned short* __restrict__ WoB,
    const float* __restrict__ bo, const float* __restrict__ x, float* __restrict__ out) {
    __shared__ __align__(16) char smem[133120];

    const int tid = threadIdx.x;
    const int lane = tid & 63, wave = tid >> 6;
    const int wj = wave & 1, wi = wave >> 1;
    const int l31 = lane & 31, h = lane >> 5;
    const int b = blockIdx.x & 7;              // batch -> XCD affinity
    const int ibase = (blockIdx.x >> 3) * 128;
    const int irow = wi * 32 + l31;            // tile-local q row this lane owns (as MFMA col)

    // global_load_lds staging: linear LDS dest, pre-swizzled global source (chunk ^ row&15).
    const char* kg[4]; const char* vg[4]; int ldsoff[4];
#pragma unroll
    for (int q = 0; q < 4; ++q) {
        int slot = (wave * 4 + q) * 64 + lane;   // 16B slot index 0..2047
        int row = slot >> 4, s = slot & 15;
        int cs = s ^ (row & 15);
        kg[q] = (const char*)(k_ws + ((size_t)b * 4096 + row) * 128 + cs * 8);  // row=j, chunk=c
        vg[q] = (const char*)(v_ws + ((size_t)b * 128 + row) * 4096 + cs * 8);  // row=c, chunk=j
        ldsoff[q] = (wave * 4 + q) * 1024;
    }
    // prologue: stage tile 0 into buffer 0
#pragma unroll
    for (int q = 0; q < 4; ++q)
        __builtin_amdgcn_global_load_lds(AS1C(kg[q]), AS3(smem + ldsoff[q]), 16, 0, 0);
#pragma unroll
    for (int q = 0; q < 4; ++q)
        __builtin_amdgcn_global_load_lds(AS1C(vg[q]), AS3(smem + 32768 + ldsoff[q]), 16, 0, 0);

    // Q fragments: B-operand, col=i, k=c
    bf16x8 qf[8];
    {
        const unsigned short* qrow = q_ws + ((size_t)b * 4096 + ibase + irow) * 128;
#pragma unroll
        for (int cc = 0; cc < 8; ++cc) qf[cc] = *(const bf16x8*)(qrow + cc * 16 + h * 8);
    }

    f32x16 oac[4];
#pragma unroll
    for (int cf = 0; cf < 4; ++cf)
#pragma unroll
        for (int r = 0; r < 16; ++r) oac[cf][r] = 0.f;
    float m = -1e30f, ssum = 0.f;

    __syncthreads();  // tile 0 staged

#pragma unroll 1
    for (int kt = 0; kt < 32; ++kt) {
        const int cur = kt & 1;
        const char* Kc = smem + cur * 65536;
        const char* Vc = Kc + 32768;
        if (kt < 31) {  // prefetch tile kt+1 into the other buffer (drained at end barrier)
            char* Kn = smem + (cur ^ 1) * 65536;
            char* Vn = Kn + 32768;
            const size_t kb = (size_t)(kt + 1) * 32768;  // 128 j * 256 B
            const size_t vb = (size_t)(kt + 1) * 256;    // 128 j * 2 B
#pragma unroll
            for (int q = 0; q < 4; ++q)
                __builtin_amdgcn_global_load_lds(AS1C(kg[q] + kb), AS3(Kn + ldsoff[q]), 16, 0, 0);
#pragma unroll
            for (int q = 0; q < 4; ++q)
                __builtin_amdgcn_global_load_lds(AS1C(vg[q] + vb), AS3(Vn + ldsoff[q]), 16, 0, 0);
        }

        // S^T[j][i] = K·Q^T over this wave's 64-j half
        f32x16 st[2];
#pragma unroll
        for (int jf = 0; jf < 2; ++jf)
#pragma unroll
            for (int r = 0; r < 16; ++r) st[jf][r] = 0.f;
#pragma unroll
        for (int jf = 0; jf < 2; ++jf) {
            const int jrow = wj * 64 + jf * 32 + l31;
#pragma unroll
            for (int cc = 0; cc < 8; ++cc) {
                unsigned byte = (unsigned)(jrow * 256 + cc * 32 + h * 16) ^ ((jrow & 15) << 4);
                bf16x8 kf = *(const bf16x8*)(Kc + byte);
                st[jf] = __builtin_amdgcn_mfma_f32_32x32x16_bf16(kf, qf[cc], st[jf], 0, 0, 0);
            }
        }

        // online softmax over this half's 64 j (32 in-lane + 1 xor32 shuffle)
        float tmax = -1e30f;
#pragma unroll
        for (int jf = 0; jf < 2; ++jf)
#pragma unroll
            for (int r = 0; r < 16; ++r) tmax = fmaxf(tmax, st[jf][r]);
        tmax = fmaxf(tmax, __shfl_xor(tmax, 32));
        if (!__all(tmax <= m)) {               // defer-rescale
            float mnew = fmaxf(m, tmax);
            float corr = __expf(m - mnew);
            ssum *= corr;
#pragma unroll
            for (int cf = 0; cf < 4; ++cf)
#pragma unroll
                for (int r = 0; r < 16; ++r) oac[cf][r] *= corr;
            m = mnew;
        }
        // pack P to bf16 pairs: u[jf][gq][w] covers j = 32jf + 8gq + 4h + (2w..2w+1)
        float psum = 0.f;
        unsigned u[2][4][2];
#pragma unroll
        for (int jf = 0; jf < 2; ++jf)
#pragma unroll
            for (int gq = 0; gq < 4; ++gq) {
                float p0 = __expf(st[jf][gq * 4 + 0] - m);
                float p1 = __expf(st[jf][gq * 4 + 1] - m);
                float p2 = __expf(st[jf][gq * 4 + 2] - m);
                float p3 = __expf(st[jf][gq * 4 + 3] - m);
                psum += (p0 + p1) + (p2 + p3);
                u[jf][gq][0] = cvtpk_bf16(p0, p1);
                u[jf][gq][1] = cvtpk_bf16(p2, p3);
            }
        psum += __shfl_xor(psum, 32);
        ssum += psum;

        // in-register cross-h exchange -> PV B-frags pa[js] (j = 16js + 8h + s, within half)
        bf16x8 pa[4];
#pragma unroll
        for (int js = 0; js < 4; ++js) {
            const int jf = js >> 1, ga = 2 * (js & 1), gb = ga + 1;
            unsigned own0 = h ? u[jf][gb][0] : u[jf][ga][0];
            unsigned own1 = h ? u[jf][gb][1] : u[jf][ga][1];
            unsigned snd0 = h ? u[jf][ga][0] : u[jf][gb][0];
            unsigned snd1 = h ? u[jf][ga][1] : u[jf][gb][1];
            unsigned rcv0 = __shfl_xor(snd0, 32);
            unsigned rcv1 = __shfl_xor(snd1, 32);
            union { unsigned w[4]; bf16x8 v; } pu;
            pu.w[0] = h ? rcv0 : own0;
            pu.w[1] = h ? rcv1 : own1;
            pu.w[2] = h ? own0 : rcv0;
            pu.w[3] = h ? own1 : rcv1;
            pa[js] = pu.v;
        }

        // out2[c][i] += V (A, rows c, k=j) x P^T (B, cols i, k=j) over this half's j
#pragma unroll
        for (int js = 0; js < 4; ++js) {
            const int jcol = wj * 64 + js * 16 + h * 8;
#pragma unroll
            for (int cf = 0; cf < 4; ++cf) {
                int crow = cf * 32 + l31;
                unsigned vbyte = (unsigned)(crow * 256 + jcol * 2) ^ ((crow & 15) << 4);
                bf16x8 va = *(const bf16x8*)(Vc + vbyte);
                oac[cf] = __builtin_amdgcn_mfma_f32_32x32x16_bf16(va, pa[js], oac[cf], 0, 0, 0);
            }
        }
        __syncthreads();  // prefetch drained + all reads of cur done -> next iter may restage
    }

    // ---- epilogue: combine the two j-halves, then fused 1x1 conv + bias + residual ----
    float* sRed = (float*)(smem + 131072);  // [8 wave][32 i][2] (m, ssum)
    if (h == 0) {
        sRed[(wave * 32 + l31) * 2] = m;
        sRed[(wave * 32 + l31) * 2 + 1] = ssum;
    }
    __syncthreads();
    float m1 = sRed[((wave ^ 1) * 32 + l31) * 2];
    float s1 = sRed[((wave ^ 1) * 32 + l31) * 2 + 1];
    float M = fmaxf(m, m1);
    float aS = __expf(m - M);
    float stot = aS * ssum + __expf(m1 - M) * s1;
    float inv = 1.0f / stot;

    float* sBig = (float*)smem;  // [4 wi][32 i][128 c] f32, swz ^((i&7)<<4), 64 KB over K0/V0
    if (wj == 1) {
#pragma unroll
        for (int cf = 0; cf < 4; ++cf)
#pragma unroll
            for (int gq = 0; gq < 4; ++gq) {
                f32x4 v4;
#pragma unroll
                for (int k = 0; k < 4; ++k) v4[k] = aS * oac[cf][gq * 4 + k];
                int cb = cf * 32 + gq * 8 + 4 * h;
                unsigned byte = (unsigned)(wi * 16384 + l31 * 512 + cb * 4) ^ ((l31 & 7) << 4);
                *(f32x4*)((char*)sBig + byte) = v4;
            }
    }
    __syncthreads();
    unsigned short* sOut = (unsigned short*)(smem + 65536);  // [128 i][128 c] bf16, swz ^((i&15)<<4)
    if (wj == 0) {
#pragma unroll
        for (int cf = 0; cf < 4; ++cf)
#pragma unroll
            for (int gq = 0; gq < 4; ++gq) {
                int cb = cf * 32 + gq * 8 + 4 * h;
                unsigned rbyte = (unsigned)(wi * 16384 + l31 * 512 + cb * 4) ^ ((l31 & 7) << 4);
                f32x4 o4 = *(const f32x4*)((const char*)sBig + rbyte);
                float t0 = (aS * oac[cf][gq * 4 + 0] + o4[0]) * inv;
                float t1 = (aS * oac[cf][gq * 4 + 1] + o4[1]) * inv;
                float t2 = (aS * oac[cf][gq * 4 + 2] + o4[2]) * inv;
                float t3 = (aS * oac[cf][gq * 4 + 3] + o4[3]) * inv;
                uint2 pk;
                pk.x = cvtpk_bf16(t0, t1);
                pk.y = cvtpk_bf16(t2, t3);
                unsigned wbyte = (unsigned)(irow * 256 + cb * 2) ^ ((irow & 15) << 4);
                *(uint2*)((char*)sOut + wbyte) = pk;
            }
    }
    __syncthreads();

    // 1x1 conv: D[o][i] = Wo x out2, 16 tiles of 32x32 over 8 waves (2 each)
#pragma unroll
    for (int t = 0; t < 2; ++t) {
        int tt = wave + t * 8;
        int of = tt >> 2, ifl = tt & 3;
        int ir = ifl * 32 + l31;
        f32x16 acc;
#pragma unroll
        for (int r = 0; r < 16; ++r) acc[r] = 0.f;
#pragma unroll
        for (int cc = 0; cc < 8; ++cc) {
            unsigned bbyte = (unsigned)(ir * 256 + cc * 32 + h * 16) ^ ((ir & 15) << 4);
            bf16x8 bfr = *(const bf16x8*)((const char*)sOut + bbyte);
            bf16x8 wa = *(const bf16x8*)(WoB + (of * 32 + l31) * 128 + cc * 16 + h * 8);
            acc = __builtin_amdgcn_mfma_f32_32x32x16_bf16(wa, bfr, acc, 0, 0, 0);
        }
        int iglob = ibase + ir;
#pragma unroll
        for (int r = 0; r < 16; ++r) {
            int o = of * 32 + (r & 3) + 8 * (r >> 2) + 4 * h;
            size_t gidx = ((size_t)b * 128 + o) * 4096 + iglob;
            out[gidx] = acc[r] + bo[o] + x[gidx];
        }
    }
}

extern "C" void kernel_launch(void* const* d_in, const int* in_sizes, int n_in,
                              void* d_out, int out_size, void* d_ws, size_t ws_size,
                              hipStream_t stream) {
    const float* x  = (const float*)d_in[0];
    const float* Wq = (const float*)d_in[1];
    const float* bq = (const float*)d_in[2];
    const float* Wk = (const float*)d_in[3];
    const float* bk = (const float*)d_in[4];
    const float* Wv = (const float*)d_in[5];
    const float* bv = (const float*)d_in[6];
    const float* Wo = (const float*)d_in[7];
    const float* bo = (const float*)d_in[8];
    char* ws = (char*)d_ws;
    unsigned short* q_ws = (unsigned short*)(ws);              //  8 MB  [b][n][c] bf16 (pre-scaled)
    unsigned short* k_ws = (unsigned short*)(ws + 8388608);    //  8 MB  [b][n][c] bf16
    unsigned short* v_ws = (unsigned short*)(ws + 16777216);   //  8 MB  [b][c][n] bf16
    unsigned short* RW   = (unsigned short*)(ws + 25165824);   //  884 KB repacked qkv weights
    unsigned short* WoB  = (unsigned short*)(ws + 26050560);   //  32 KB  Wo bf16
    float* out = (float*)d_out;

    hipLaunchKernelGGL(repack_k, dim3(1792), dim3(256), 0, stream, Wq, Wk, Wv, Wo, RW, WoB);
    hipLaunchKernelGGL(qkv_conv_k, dim3(512), dim3(256), 0, stream, x, RW, bq, bk, bv, q_ws, k_ws, v_ws);
    hipLaunchKernelGGL(attn_k, dim3(256), dim3(512), 0, stream, q_ws, k_ws, v_ws, WoB, bo, x, out);
}